// Round 4
// baseline (604.377 us; speedup 1.0000x reference)
//
#include <hip/hip_runtime.h>

typedef __bf16 bf16;
typedef __bf16 bf16x4 __attribute__((ext_vector_type(4)));
typedef __bf16 bf16x8 __attribute__((ext_vector_type(8)));
typedef float f32x4 __attribute__((ext_vector_type(4)));

#define S_LEN 2048
#define HID   3584
#define NHEADS 16
#define NKVH   8
#define HDIM   256
#define QKV_O  8192   // (16 + 2*8) * 256
#define O_IN   4096   // 16 * 256

typedef const __attribute__((address_space(1))) void* gp_t;
typedef __attribute__((address_space(3))) void* sp_t;

__device__ __forceinline__ void async16(const void* g, void* s) {
  __builtin_amdgcn_global_load_lds((gp_t)g, (sp_t)s, 16, 0, 0);
}

__device__ __forceinline__ f32x4 mfma16(bf16x8 a, bf16x8 b, f32x4 c) {
  return __builtin_amdgcn_mfma_f32_16x16x32_bf16(a, b, c, 0, 0, 0);
}

// ---------------- fp32 -> bf16 cast (4 elems/thread) ----------------
__global__ __launch_bounds__(256) void cast_kernel(const float* __restrict__ in,
                                                   bf16* __restrict__ out, int n4) {
  int i = blockIdx.x * 256 + threadIdx.x;
  if (i >= n4) return;
  f32x4 v = ((const f32x4*)in)[i];
  bf16x4 o = { (bf16)v[0], (bf16)v[1], (bf16)v[2], (bf16)v[3] };
  ((bf16x4*)out)[i] = o;
}

// ---------------- fp32 partial-sum reduce: out = a + b (4 elems/thread) ----------------
__global__ __launch_bounds__(256) void add2_kernel(const float* __restrict__ a,
                                                   const float* __restrict__ b,
                                                   float* __restrict__ o, int n4) {
  int i = blockIdx.x * 256 + threadIdx.x;
  if (i >= n4) return;
  f32x4 x = ((const f32x4*)a)[i];
  f32x4 y = ((const f32x4*)b)[i];
  ((f32x4*)o)[i] = x + y;
}

// ---------------- 8-phase 256x256 NT bf16 GEMM (QKV projection) ----------------
// Frozen at R3 state (131us, 907 TF, MfmaUtil 37.5%): symmetric 8-wave lockstep at
// 1 block/CU bounds this structure; fragment dbuf would drop to 1 wave/SIMD
// (248/256 VGPR now). See R1-R3 notes. Single barrier/phase, counted vmcnt(4) at
// P4/P8, stage-issue at phase start, setprio on MFMA, chunk-XOR swizzle (0 conf),
// 2x16 rect XCD swizzle.
__global__ __launch_bounds__(512, 2) void gemm_nt_8p(const bf16* __restrict__ A,
                                                     const bf16* __restrict__ B,
                                                     float* __restrict__ C,
                                                     int M, int N, int K) {
  __shared__ bf16 As0[256 * 64];
  __shared__ bf16 Bs0[256 * 64];
  __shared__ bf16 As1[256 * 64];
  __shared__ bf16 Bs1[256 * 64];
  int tid = threadIdx.x;
  int lane = tid & 63;
  int w = tid >> 6;
  int wm = w >> 2, wn = w & 3;
  int lid = blockIdx.x;
  int oid = (lid & 7) * 32 + (lid >> 3);
  int rect = oid >> 5, ri = oid & 31;
  int bm = (rect & 3) * 2 + (ri >> 4);
  int bn = (rect >> 2) * 16 + (ri & 15);
  int srow = tid >> 3, schunk = tid & 7;
  int gcol = (schunk ^ (srow & 7)) * 8;
  const bf16* Ag = A + (size_t)(bm * 256 + srow) * K + gcol;
  const bf16* Bg = B + (size_t)(bn * 256 + srow) * K + gcol;
  int soff = srow * 64 + schunk * 8;
  int fr = lane & 15, fq = lane >> 4;
  int c0 = ((fq) ^ (fr & 7)) * 8;
  int c1 = ((4 + fq) ^ (fr & 7)) * 8;
  const int arow = (wm * 128 + fr) * 64;
  const int brow = (wn * 64 + fr) * 64;

  f32x4 acc[8][4];
#pragma unroll
  for (int i = 0; i < 8; i++)
#pragma unroll
    for (int j = 0; j < 4; j++) { f32x4 z = {0.f, 0.f, 0.f, 0.f}; acc[i][j] = z; }
  bf16x8 a[8], b[8];

#define STG(gb, lb, kk, half) do {                                    \
    const bf16* _g = (gb) + (size_t)((half) * 128) * K + (kk);        \
    bf16* _l = (lb) + (half) * 128 * 64 + soff;                       \
    async16(_g, _l);                                                  \
    async16(_g + (size_t)64 * K, _l + 64 * 64);                       \
  } while (0)
#define LDA8(base, mg) do {                                           \
    const bf16* _p = (base) + arow + (mg) * 64 * 64;                  \
    _Pragma("unroll")                                                 \
    for (int i = 0; i < 4; i++) {                                     \
      a[i * 2 + 0] = *(const bf16x8*)(_p + i * 16 * 64 + c0);         \
      a[i * 2 + 1] = *(const bf16x8*)(_p + i * 16 * 64 + c1);         \
    }                                                                 \
  } while (0)
#define LDB4(base, jh) do {                                           \
    const bf16* _p = (base) + brow + (jh) * 32 * 64;                  \
    _Pragma("unroll")                                                 \
    for (int j = 0; j < 2; j++) {                                     \
      b[(jh) * 4 + j * 2 + 0] = *(const bf16x8*)(_p + j * 16 * 64 + c0); \
      b[(jh) * 4 + j * 2 + 1] = *(const bf16x8*)(_p + j * 16 * 64 + c1); \
    }                                                                 \
  } while (0)
#define MM16(mg, jh) do {                                             \
    __builtin_amdgcn_s_setprio(1);                                    \
    _Pragma("unroll")                                                 \
    for (int i = 0; i < 4; i++) {                                     \
      acc[(mg) * 4 + i][(jh) * 2 + 0] = mfma16(a[i * 2 + 0], b[(jh) * 4 + 0], acc[(mg) * 4 + i][(jh) * 2 + 0]); \
      acc[(mg) * 4 + i][(jh) * 2 + 0] = mfma16(a[i * 2 + 1], b[(jh) * 4 + 1], acc[(mg) * 4 + i][(jh) * 2 + 0]); \
      acc[(mg) * 4 + i][(jh) * 2 + 1] = mfma16(a[i * 2 + 0], b[(jh) * 4 + 2], acc[(mg) * 4 + i][(jh) * 2 + 1]); \
      acc[(mg) * 4 + i][(jh) * 2 + 1] = mfma16(a[i * 2 + 1], b[(jh) * 4 + 3], acc[(mg) * 4 + i][(jh) * 2 + 1]); \
    }                                                                 \
    __builtin_amdgcn_s_setprio(0);                                    \
  } while (0)
#define BAR() __builtin_amdgcn_s_barrier()
#define SBZ() __builtin_amdgcn_sched_barrier(0)
#define WAITV4() asm volatile("s_waitcnt vmcnt(4)" ::: "memory")

  const int nT = K >> 6;
  const int nIter = K >> 7;
  STG(Ag, As0, 0, 0); STG(Ag, As0, 0, 1);
  STG(Bg, Bs0, 0, 0); STG(Bg, Bs0, 0, 1);
  STG(Bg, Bs1, 64, 0); STG(Bg, Bs1, 64, 1);
  WAITV4();
  BAR(); SBZ();

  for (int t = 0; t < nIter; t++) {
    int T = 2 * t;
    int kA1 = (T + 1) * 64;
    int t2 = T + 2; if (t2 > nT - 1) t2 = nT - 1;
    int t3 = T + 3; if (t3 > nT - 1) t3 = nT - 1;
    int k2 = t2 * 64, k3 = t3 * 64;
    // P1
    STG(Ag, As1, kA1, 0);
    LDA8(As0, 0); LDB4(Bs0, 0);
    MM16(0, 0); BAR();
    // P2
    STG(Ag, As1, kA1, 1);
    LDB4(Bs0, 1);
    MM16(0, 1); BAR();
    // P3
    STG(Bg, Bs0, k2, 0);
    LDA8(As0, 1);
    MM16(1, 0); BAR();
    // P4
    STG(Bg, Bs0, k2, 1);
    MM16(1, 1); WAITV4(); BAR(); SBZ();
    // P5
    STG(Ag, As0, k2, 0);
    LDA8(As1, 0); LDB4(Bs1, 0);
    MM16(0, 0); BAR();
    // P6
    STG(Ag, As0, k2, 1);
    LDB4(Bs1, 1);
    MM16(0, 1); BAR();
    // P7
    STG(Bg, Bs1, k3, 0);
    LDA8(As1, 1);
    MM16(1, 0); BAR();
    // P8
    STG(Bg, Bs1, k3, 1);
    MM16(1, 1); WAITV4(); BAR(); SBZ();
  }
#undef STG
#undef LDA8
#undef LDB4
#undef MM16
#undef BAR
#undef SBZ
#undef WAITV4

  int row0 = bm * 256 + wm * 128 + fq * 4;
  int col0 = bn * 256 + wn * 64 + fr;
#pragma unroll
  for (int i = 0; i < 8; i++)
#pragma unroll
    for (int j = 0; j < 4; j++)
#pragma unroll
      for (int r = 0; r < 4; r++)
        C[(size_t)(row0 + i * 16 + r) * N + col0 + j * 16] = acc[i][j][r];
}

// ---------------- split-K=2 variant for the output projection ----------------
// N=3584 -> only 112 tiles of 256^2 (44% CU util). Split K=4096 into 2 halves:
// 224 blocks (87% util), each runs K=2048 with lda=4096; partial C written to
// C + ks*M*N (fp32, reused qkv workspace); add2_kernel reduces. Block mapping:
// ks = lid>=112; per-half XCD swizzle oid=(l2&7)*14+(l2>>3) (bijective, 112%8==0):
// XCD x gets bm=x for both halves -> A-panels L2-resident.
__global__ __launch_bounds__(512, 2) void gemm_nt_8p_ks(const bf16* __restrict__ A,
                                                        const bf16* __restrict__ B,
                                                        float* __restrict__ C,
                                                        int M, int N, int K, int lda) {
  __shared__ bf16 As0[256 * 64];
  __shared__ bf16 Bs0[256 * 64];
  __shared__ bf16 As1[256 * 64];
  __shared__ bf16 Bs1[256 * 64];
  int tid = threadIdx.x;
  int lane = tid & 63;
  int w = tid >> 6;
  int wm = w >> 2, wn = w & 3;
  int lid = blockIdx.x;
  int ks = lid >= 112;
  int l2 = lid - ks * 112;
  int oid = (l2 & 7) * 14 + (l2 >> 3);
  int bm = oid / 14;
  int bn = oid - bm * 14;
  int kbase = ks * K;
  float* Cp = C + (size_t)ks * M * N;
  int srow = tid >> 3, schunk = tid & 7;
  int gcol = (schunk ^ (srow & 7)) * 8;
  const bf16* Ag = A + (size_t)(bm * 256 + srow) * lda + kbase + gcol;
  const bf16* Bg = B + (size_t)(bn * 256 + srow) * lda + kbase + gcol;
  int soff = srow * 64 + schunk * 8;
  int fr = lane & 15, fq = lane >> 4;
  int c0 = ((fq) ^ (fr & 7)) * 8;
  int c1 = ((4 + fq) ^ (fr & 7)) * 8;
  const int arow = (wm * 128 + fr) * 64;
  const int brow = (wn * 64 + fr) * 64;

  f32x4 acc[8][4];
#pragma unroll
  for (int i = 0; i < 8; i++)
#pragma unroll
    for (int j = 0; j < 4; j++) { f32x4 z = {0.f, 0.f, 0.f, 0.f}; acc[i][j] = z; }
  bf16x8 a[8], b[8];

#define STG(gb, lb, kk, half) do {                                    \
    const bf16* _g = (gb) + (size_t)((half) * 128) * lda + (kk);      \
    bf16* _l = (lb) + (half) * 128 * 64 + soff;                       \
    async16(_g, _l);                                                  \
    async16(_g + (size_t)64 * lda, _l + 64 * 64);                     \
  } while (0)
#define LDA8(base, mg) do {                                           \
    const bf16* _p = (base) + arow + (mg) * 64 * 64;                  \
    _Pragma("unroll")                                                 \
    for (int i = 0; i < 4; i++) {                                     \
      a[i * 2 + 0] = *(const bf16x8*)(_p + i * 16 * 64 + c0);         \
      a[i * 2 + 1] = *(const bf16x8*)(_p + i * 16 * 64 + c1);         \
    }                                                                 \
  } while (0)
#define LDB4(base, jh) do {                                           \
    const bf16* _p = (base) + brow + (jh) * 32 * 64;                  \
    _Pragma("unroll")                                                 \
    for (int j = 0; j < 2; j++) {                                     \
      b[(jh) * 4 + j * 2 + 0] = *(const bf16x8*)(_p + j * 16 * 64 + c0); \
      b[(jh) * 4 + j * 2 + 1] = *(const bf16x8*)(_p + j * 16 * 64 + c1); \
    }                                                                 \
  } while (0)
#define MM16(mg, jh) do {                                             \
    __builtin_amdgcn_s_setprio(1);                                    \
    _Pragma("unroll")                                                 \
    for (int i = 0; i < 4; i++) {                                     \
      acc[(mg) * 4 + i][(jh) * 2 + 0] = mfma16(a[i * 2 + 0], b[(jh) * 4 + 0], acc[(mg) * 4 + i][(jh) * 2 + 0]); \
      acc[(mg) * 4 + i][(jh) * 2 + 0] = mfma16(a[i * 2 + 1], b[(jh) * 4 + 1], acc[(mg) * 4 + i][(jh) * 2 + 0]); \
      acc[(mg) * 4 + i][(jh) * 2 + 1] = mfma16(a[i * 2 + 0], b[(jh) * 4 + 2], acc[(mg) * 4 + i][(jh) * 2 + 1]); \
      acc[(mg) * 4 + i][(jh) * 2 + 1] = mfma16(a[i * 2 + 1], b[(jh) * 4 + 3], acc[(mg) * 4 + i][(jh) * 2 + 1]); \
    }                                                                 \
    __builtin_amdgcn_s_setprio(0);                                    \
  } while (0)
#define BAR() __builtin_amdgcn_s_barrier()
#define SBZ() __builtin_amdgcn_sched_barrier(0)
#define WAITV4() asm volatile("s_waitcnt vmcnt(4)" ::: "memory")

  const int nT = K >> 6;
  const int nIter = K >> 7;
  STG(Ag, As0, 0, 0); STG(Ag, As0, 0, 1);
  STG(Bg, Bs0, 0, 0); STG(Bg, Bs0, 0, 1);
  STG(Bg, Bs1, 64, 0); STG(Bg, Bs1, 64, 1);
  WAITV4();
  BAR(); SBZ();

  for (int t = 0; t < nIter; t++) {
    int T = 2 * t;
    int kA1 = (T + 1) * 64;
    int t2 = T + 2; if (t2 > nT - 1) t2 = nT - 1;
    int t3 = T + 3; if (t3 > nT - 1) t3 = nT - 1;
    int k2 = t2 * 64, k3 = t3 * 64;
    // P1
    STG(Ag, As1, kA1, 0);
    LDA8(As0, 0); LDB4(Bs0, 0);
    MM16(0, 0); BAR();
    // P2
    STG(Ag, As1, kA1, 1);
    LDB4(Bs0, 1);
    MM16(0, 1); BAR();
    // P3
    STG(Bg, Bs0, k2, 0);
    LDA8(As0, 1);
    MM16(1, 0); BAR();
    // P4
    STG(Bg, Bs0, k2, 1);
    MM16(1, 1); WAITV4(); BAR(); SBZ();
    // P5
    STG(Ag, As0, k2, 0);
    LDA8(As1, 0); LDB4(Bs1, 0);
    MM16(0, 0); BAR();
    // P6
    STG(Ag, As0, k2, 1);
    LDB4(Bs1, 1);
    MM16(0, 1); BAR();
    // P7
    STG(Bg, Bs1, k3, 0);
    LDA8(As1, 1);
    MM16(1, 0); BAR();
    // P8
    STG(Bg, Bs1, k3, 1);
    MM16(1, 1); WAITV4(); BAR(); SBZ();
  }
#undef STG
#undef LDA8
#undef LDB4
#undef MM16
#undef BAR
#undef SBZ
#undef WAITV4

  int row0 = bm * 256 + wm * 128 + fq * 4;
  int col0 = bn * 256 + wn * 64 + fr;
#pragma unroll
  for (int i = 0; i < 8; i++)
#pragma unroll
    for (int j = 0; j < 4; j++)
#pragma unroll
      for (int r = 0; r < 4; r++)
        Cp[(size_t)(row0 + i * 16 + r) * N + col0 + j * 16] = acc[i][j][r];
}

// ---------------- RMSNorm + RoPE + q-scale; one wave per (s, head) ----------------
__global__ __launch_bounds__(256) void qk_norm_rope(const float* __restrict__ qkv,
                                                    const float* __restrict__ cosb,
                                                    const float* __restrict__ sinb,
                                                    const float* __restrict__ qw,
                                                    const float* __restrict__ kw,
                                                    bf16* __restrict__ qout,
                                                    bf16* __restrict__ kout) {
  int s = blockIdx.x;
  int lane = threadIdx.x & 63;
  int w = threadIdx.x >> 6;
  int d0 = lane * 4;
  int dr = d0 & 127;
  f32x4 cv = *(const f32x4*)(cosb + s * 128 + dr);
  f32x4 sv = *(const f32x4*)(sinb + s * 128 + dr);
  bool hi = lane >= 32;
#pragma unroll
  for (int r = 0; r < 6; r++) {
    int head = r * 4 + w;  // 0..23 : 16 q heads then 8 k heads
    const float* x = qkv + (size_t)s * QKV_O + head * HDIM + d0;
    f32x4 v = *(const f32x4*)x;
    float ss = v[0] * v[0] + v[1] * v[1] + v[2] * v[2] + v[3] * v[3];
#pragma unroll
    for (int off = 32; off > 0; off >>= 1) ss += __shfl_xor(ss, off);
    float scale = rsqrtf(ss * (1.0f / HDIM) + 1e-6f);
    bool isq = head < NHEADS;
    const float* wn = isq ? qw : kw;
    f32x4 wv = *(const f32x4*)(wn + d0);
    float y[4], o[4];
#pragma unroll
    for (int i = 0; i < 4; i++) y[i] = v[i] * scale * (1.0f + wv[i]);
#pragma unroll
    for (int i = 0; i < 4; i++) {
      float py = __shfl_xor(y[i], 32);
      o[i] = hi ? (py * sv[i] + y[i] * cv[i]) : (y[i] * cv[i] - py * sv[i]);
    }
    float mult = isq ? 0.0625f : 1.0f;  // SCALING = 256^-0.5 folded into q
    bf16x4 ov = { (bf16)(o[0] * mult), (bf16)(o[1] * mult), (bf16)(o[2] * mult), (bf16)(o[3] * mult) };
    if (isq) *(bf16x4*)(qout + ((size_t)head * S_LEN + s) * HDIM + d0) = ov;
    else     *(bf16x4*)(kout + ((size_t)(head - NHEADS) * S_LEN + s) * HDIM + d0) = ov;
  }
}

// ---------------- V transpose: qkv fp32 [s][6144+h*256+d] -> vt bf16 [h][d][s] ----------------
__global__ __launch_bounds__(256) void v_transpose(const float* __restrict__ qkv, bf16* __restrict__ vt) {
  __shared__ float tile[64][65];
  int dt = blockIdx.x, st = blockIdx.y, h = blockIdx.z;
  int t = threadIdx.x;
  int d0 = dt * 64, s0 = st * 64;
#pragma unroll
  for (int i = 0; i < 16; i++) {
    int idx = i * 256 + t;
    int r = idx >> 6, c = idx & 63;
    tile[r][c] = qkv[(size_t)(s0 + r) * QKV_O + 6144 + h * HDIM + d0 + c];
  }
  __syncthreads();
#pragma unroll
  for (int i = 0; i < 16; i++) {
    int idx = i * 256 + t;
    int dr = idx >> 6, sc = idx & 63;
    vt[((size_t)h * HDIM + d0 + dr) * S_LEN + s0 + sc] = (bf16)tile[sc][dr];
  }
}

// ---------------- Flash attention: 64 q-rows/block, Bk=32 ----------------
#define PSTRIDE 40
__global__ __launch_bounds__(256) void attn_kernel(const bf16* __restrict__ q,
                                                   const bf16* __restrict__ kx,
                                                   const bf16* __restrict__ vt,
                                                   bf16* __restrict__ aout) {
  __shared__ bf16 kt[32 * 256];
  __shared__ bf16 vtile[256 * 32];
  __shared__ bf16 pbuf[4][16 * PSTRIDE];
  int h = blockIdx.x;
  int y = blockIdx.y;
  int qt = (y < 16) ? y : 47 - y;
  int kvh = h >> 1;
  int tid = threadIdx.x;
  int lane = tid & 63, w = tid >> 6;
  int fr = lane & 15, fq = lane >> 4;
  int qs = qt * 64;
  bf16x8 qf[8];
  const bf16* qb = q + ((size_t)h * S_LEN + qs + w * 16 + fr) * HDIM + fq * 8;
#pragma unroll
  for (int i = 0; i < 8; i++) qf[i] = *(const bf16x8*)(qb + i * 32);
  f32x4 acc[16];
#pragma unroll
  for (int i = 0; i < 16; i++) { f32x4 z = {0.f, 0.f, 0.f, 0.f}; acc[i] = z; }
  float lsum[4] = {0.f, 0.f, 0.f, 0.f};
  int krow = w * 2 + (lane >> 5);
  int kcolr = (lane & 31) * 8;
  const bf16* kg = kx + (size_t)kvh * S_LEN * HDIM;
  int vd = w * 16 + (lane >> 2);
  int vsw = (vd >> 1) & 3;
  int vcl = (lane & 3) * 8;
  int vcg = (((lane & 3) ^ vsw) * 8);
  const bf16* vg = vt + (size_t)kvh * HDIM * S_LEN;
  int rot0 = (fq * 8 - fr * 8) & 255;
  int rot1 = (fq * 8 - fr * 8 - 128) & 255;
  const bf16* kt0 = &kt[fr * 256];
  const bf16* kt1 = &kt[(16 + fr) * 256];
  int fsw = (fr >> 1) & 3;
  int kmax = qs + 64;
  for (int k0 = 0; k0 < kmax; k0 += 32) {
    __syncthreads();
#pragma unroll
    for (int p = 0; p < 4; p++) {
      int r = p * 8 + krow;
      int gc = (kcolr + r * 8) & 255;
      async16(kg + (size_t)(k0 + r) * HDIM + gc, &kt[r * 256 + kcolr]);
      int d = p * 64 + vd;
      async16(vg + (size_t)d * S_LEN + k0 + vcg, &vtile[d * 32 + vcl]);
    }
    __syncthreads();
    f32x4 s0 = {0.f, 0.f, 0.f, 0.f}, s1 = {0.f, 0.f, 0.f, 0.f};
#pragma unroll
    for (int kk = 0; kk < 8; kk++) {
      bf16x8 b0 = *(const bf16x8*)(kt0 + ((kk * 32 + rot0) & 255));
      bf16x8 b1 = *(const bf16x8*)(kt1 + ((kk * 32 + rot1) & 255));
      s0 = mfma16(qf[kk], b0, s0);
      s1 = mfma16(qf[kk], b1, s1);
    }
#pragma unroll
    for (int reg = 0; reg < 4; reg++) {
      int rowg = qs + w * 16 + fq * 4 + reg;
      float u0 = __builtin_amdgcn_exp2f(0.057707802f * s0[reg]);
      float u1 = __builtin_amdgcn_exp2f(0.057707802f * s1[reg]);
      float p0 = __builtin_amdgcn_exp2f(28.853901f - 144.26950f * __builtin_amdgcn_rcpf(u0 + 1.0f));
      float p1 = __builtin_amdgcn_exp2f(28.853901f - 144.26950f * __builtin_amdgcn_rcpf(u1 + 1.0f));
      p0 = (k0 + fr <= rowg) ? p0 : 0.0f;
      p1 = (k0 + 16 + fr <= rowg) ? p1 : 0.0f;
      lsum[reg] += p0 + p1;
      pbuf[w][(fq * 4 + reg) * PSTRIDE + fr] = (bf16)p0;
      pbuf[w][(fq * 4 + reg) * PSTRIDE + 16 + fr] = (bf16)p1;
    }
    bf16x8 pf = *(const bf16x8*)&pbuf[w][fr * PSTRIDE + fq * 8];
#pragma unroll
    for (int ct = 0; ct < 16; ct++) {
      bf16x8 vf = *(const bf16x8*)&vtile[(ct * 16 + fr) * 32 + (fq ^ fsw) * 8];
      acc[ct] = mfma16(pf, vf, acc[ct]);
    }
  }
  float rl[4];
#pragma unroll
  for (int reg = 0; reg < 4; reg++) {
    float l = lsum[reg];
    l += __shfl_xor(l, 1);
    l += __shfl_xor(l, 2);
    l += __shfl_xor(l, 4);
    l += __shfl_xor(l, 8);
    rl[reg] = 1.0f / l;
  }
#pragma unroll
  for (int ct = 0; ct < 16; ct++)
#pragma unroll
    for (int reg = 0; reg < 4; reg++)
      aout[(size_t)(qs + w * 16 + fq * 4 + reg) * O_IN + h * HDIM + ct * 16 + fr] =
          (bf16)(acc[ct][reg] * rl[reg]);
}

extern "C" void kernel_launch(void* const* d_in, const int* in_sizes, int n_in,
                              void* d_out, int out_size, void* d_ws, size_t ws_size,
                              hipStream_t stream) {
  const float* hidden = (const float*)d_in[0];
  const float* cosb   = (const float*)d_in[1];
  const float* sinb   = (const float*)d_in[2];
  const float* wqkv   = (const float*)d_in[7];
  const float* wo     = (const float*)d_in[8];
  const float* qnw    = (const float*)d_in[9];
  const float* knw    = (const float*)d_in[10];
  float* out = (float*)d_out;
  char* ws = (char*)d_ws;
  bf16*  h_bf    = (bf16*)(ws + 0);          // 2048*3584*2   = 14,680,064
  bf16*  wqkv_bf = (bf16*)(ws + 14680064);   // 8192*3584*2   = 58,720,256
  bf16*  wo_bf   = (bf16*)(ws + 73400320);   // 3584*4096*2   = 29,360,128
  float* qkv     = (float*)(ws + 102760448); // 2048*8192*4   = 67,108,864
  bf16*  qb      = (bf16*)(ws + 169869312);  // 16*2048*256*2 = 16,777,216
  bf16*  kb      = (bf16*)(ws + 186646528);  // 8*2048*256*2  =  8,388,608
  bf16*  vtb     = (bf16*)(ws + 195035136);  // 8*256*2048*2  =  8,388,608
  bf16*  attnb   = (bf16*)(ws + 203423744);  // 2048*4096*2   = 16,777,216
  // split-K partials reuse the qkv region (dead after qk_norm_rope + v_transpose):
  // 2 x 2048*3584*4 = 58,720,256 <= 67,108,864
  float* part0   = (float*)(ws + 102760448);
  float* part1   = part0 + (size_t)2048 * 3584;

  cast_kernel<<<7168, 256, 0, stream>>>(hidden, h_bf, 1835008);
  cast_kernel<<<28672, 256, 0, stream>>>(wqkv, wqkv_bf, 7340032);
  cast_kernel<<<14336, 256, 0, stream>>>(wo, wo_bf, 3670016);
  gemm_nt_8p<<<256, 512, 0, stream>>>(h_bf, wqkv_bf, qkv, 2048, 8192, 3584);
  qk_norm_rope<<<2048, 256, 0, stream>>>(qkv, cosb, sinb, qnw, knw, qb, kb);
  v_transpose<<<dim3(4, 32, 8), 256, 0, stream>>>(qkv, vtb);
  attn_kernel<<<dim3(16, 32), 256, 0, stream>>>(qb, kb, vtb, attnb);
  gemm_nt_8p_ks<<<224, 512, 0, stream>>>(attnb, wo_bf, part0, 2048, 3584, 2048, 4096);
  add2_kernel<<<7168, 256, 0, stream>>>(part0, part1, out, 1835008);
}

// Round 5
// 579.972 us; speedup vs baseline: 1.0421x; 1.0421x over previous
//
#include <hip/hip_runtime.h>

typedef __bf16 bf16;
typedef __bf16 bf16x4 __attribute__((ext_vector_type(4)));
typedef __bf16 bf16x8 __attribute__((ext_vector_type(8)));
typedef float f32x4 __attribute__((ext_vector_type(4)));

#define S_LEN 2048
#define HID   3584
#define NHEADS 16
#define NKVH   8
#define HDIM   256
#define QKV_O  8192   // (16 + 2*8) * 256
#define O_IN   4096   // 16 * 256

typedef const __attribute__((address_space(1))) void* gp_t;
typedef __attribute__((address_space(3))) void* sp_t;

__device__ __forceinline__ void async16(const void* g, void* s) {
  __builtin_amdgcn_global_load_lds((gp_t)g, (sp_t)s, 16, 0, 0);
}

__device__ __forceinline__ f32x4 mfma16(bf16x8 a, bf16x8 b, f32x4 c) {
  return __builtin_amdgcn_mfma_f32_16x16x32_bf16(a, b, c, 0, 0, 0);
}

// ---------------- fp32 -> bf16 cast (4 elems/thread) ----------------
__global__ __launch_bounds__(256) void cast_kernel(const float* __restrict__ in,
                                                   bf16* __restrict__ out, int n4) {
  int i = blockIdx.x * 256 + threadIdx.x;
  if (i >= n4) return;
  f32x4 v = ((const f32x4*)in)[i];
  bf16x4 o = { (bf16)v[0], (bf16)v[1], (bf16)v[2], (bf16)v[3] };
  ((bf16x4*)out)[i] = o;
}

// ---------------- fp32 partial-sum reduce: out = a + b (4 elems/thread) ----------------
__global__ __launch_bounds__(256) void add2_kernel(const float* __restrict__ a,
                                                   const float* __restrict__ b,
                                                   float* __restrict__ o, int n4) {
  int i = blockIdx.x * 256 + threadIdx.x;
  if (i >= n4) return;
  f32x4 x = ((const f32x4*)a)[i];
  f32x4 y = ((const f32x4*)b)[i];
  ((f32x4*)o)[i] = x + y;
}

// ================= shared GEMM machinery (256x256 tile, 8 waves 2Mx4N) =============
// R5: register-fragment pipelining. 4 phases per 2 K-tiles; every 32-MFMA cluster
// consumes frags ds_read in the PREVIOUS phase (cur/nxt reg sets), so LDS-read
// execution overlaps MFMA execution within each wave. Slice split: slice0 = all
// c0-chunk frags (a0[8],b0[4]), slice1 = c1 (a1,b1); acc += a_s0 x b_s0 + a_s1 x b_s1
// == the old interleaved pairing exactly.
// WAR guard: one lgkmcnt(0)+barrier per tile before restaging that tile's buffer
// (covers both the in-phase slice1 reads and the boundary slice0 reads issued in the
// prior phase). Freshness: counted vmcnt(8) (= the 8 just-issued async16, so the
// PREVIOUS 8-batch is complete) + barrier before first read of a restaged buffer.
// sched_barrier(0) after every s_barrier: raw s_barrier is NOT a compiler memory
// fence; the pin stops STG/ds_read from drifting across it.
#define GSTG(gb, lb, kk, half, LDAB) do {                              \
    const bf16* _g = (gb) + (size_t)((half) * 128) * (LDAB) + (kk);    \
    bf16* _l = (lb) + (half) * 128 * 64 + soff;                        \
    async16(_g, _l);                                                   \
    async16(_g + (size_t)64 * (LDAB), _l + 64 * 64);                   \
  } while (0)
#define LD12(ab, bb, cx, ar, br) do {                                  \
    const bf16* _pa = (ab) + arow;                                     \
    const bf16* _pb = (bb) + brow;                                     \
    _Pragma("unroll")                                                  \
    for (int _i = 0; _i < 8; _i++) ar[_i] = *(const bf16x8*)(_pa + _i * 16 * 64 + (cx)); \
    _Pragma("unroll")                                                  \
    for (int _j = 0; _j < 4; _j++) br[_j] = *(const bf16x8*)(_pb + _j * 16 * 64 + (cx)); \
  } while (0)
#define MM32(ar, br) do {                                              \
    __builtin_amdgcn_s_setprio(1);                                     \
    _Pragma("unroll")                                                  \
    for (int _i = 0; _i < 8; _i++)                                     \
      _Pragma("unroll")                                                \
      for (int _j = 0; _j < 4; _j++)                                   \
        acc[_i][_j] = mfma16(ar[_i], br[_j], acc[_i][_j]);             \
    __builtin_amdgcn_s_setprio(0);                                     \
  } while (0)
#define BARS() do { __builtin_amdgcn_s_barrier(); __builtin_amdgcn_sched_barrier(0); } while (0)
#define LGKM0() asm volatile("s_waitcnt lgkmcnt(0)" ::: "memory")
#define WAITV8() asm volatile("s_waitcnt vmcnt(8)" ::: "memory")

// Body shared by both GEMMs; LDAB = row stride of A/B in elements.
#define GEMM_PIPE_BODY(LDAB)                                           \
  f32x4 acc[8][4];                                                     \
  _Pragma("unroll")                                                    \
  for (int i = 0; i < 8; i++)                                          \
    _Pragma("unroll")                                                  \
    for (int j = 0; j < 4; j++) { f32x4 z = {0.f, 0.f, 0.f, 0.f}; acc[i][j] = z; } \
  bf16x8 a0[8], b0[4], a1[8], b1[4];                                   \
  const int nT = K >> 6;                                               \
  const int nIter = K >> 7;                                            \
  GSTG(Ag, As0, 0, 0, LDAB); GSTG(Ag, As0, 0, 1, LDAB);                \
  GSTG(Bg, Bs0, 0, 0, LDAB); GSTG(Bg, Bs0, 0, 1, LDAB);                \
  GSTG(Ag, As1, 64, 0, LDAB); GSTG(Ag, As1, 64, 1, LDAB);              \
  GSTG(Bg, Bs1, 64, 0, LDAB); GSTG(Bg, Bs1, 64, 1, LDAB);              \
  WAITV8();                                                            \
  BARS();                                                              \
  LD12(As0, Bs0, c0, a0, b0);                                          \
  for (int t = 0; t < nIter; t++) {                                    \
    int t2 = 2 * t + 2; if (t2 > nT - 1) t2 = nT - 1;                  \
    int t3 = 2 * t + 3; if (t3 > nT - 1) t3 = nT - 1;                  \
    int k2 = t2 * 64, k3 = t3 * 64;                                    \
    /* Ph1: tile even (buf0) — load slice1, compute slice0 */          \
    LD12(As0, Bs0, c1, a1, b1);                                        \
    MM32(a0, b0);                                                      \
    LGKM0();                                                           \
    BARS();                                                            \
    /* Ph2: restage buf0, compute slice1, publish buf1, fetch odd s0 */\
    GSTG(Ag, As0, k2, 0, LDAB); GSTG(Ag, As0, k2, 1, LDAB);            \
    GSTG(Bg, Bs0, k2, 0, LDAB); GSTG(Bg, Bs0, k2, 1, LDAB);            \
    MM32(a1, b1);                                                      \
    WAITV8();                                                          \
    BARS();                                                            \
    LD12(As1, Bs1, c0, a0, b0);                                        \
    /* Ph3: tile odd (buf1) */                                         \
    LD12(As1, Bs1, c1, a1, b1);                                        \
    MM32(a0, b0);                                                      \
    LGKM0();                                                           \
    BARS();                                                            \
    /* Ph4 */                                                          \
    GSTG(Ag, As1, k3, 0, LDAB); GSTG(Ag, As1, k3, 1, LDAB);            \
    GSTG(Bg, Bs1, k3, 0, LDAB); GSTG(Bg, Bs1, k3, 1, LDAB);            \
    MM32(a1, b1);                                                      \
    WAITV8();                                                          \
    BARS();                                                            \
    LD12(As0, Bs0, c0, a0, b0);                                        \
  }

// ---------------- 8-wave 256x256 NT bf16 GEMM (QKV projection) ----------------
__global__ __launch_bounds__(512, 2) void gemm_nt_8p(const bf16* __restrict__ A,
                                                     const bf16* __restrict__ B,
                                                     float* __restrict__ C,
                                                     int M, int N, int K) {
  __shared__ bf16 As0[256 * 64];
  __shared__ bf16 Bs0[256 * 64];
  __shared__ bf16 As1[256 * 64];
  __shared__ bf16 Bs1[256 * 64];
  int tid = threadIdx.x;
  int lane = tid & 63;
  int w = tid >> 6;
  int wm = w >> 2, wn = w & 3;
  // XCD rect swizzle (grid=256, nbn=32): XCD x gets one 2x16 (bm x bn) rectangle.
  int lid = blockIdx.x;
  int oid = (lid & 7) * 32 + (lid >> 3);
  int rect = oid >> 5, ri = oid & 31;
  int bm = (rect & 3) * 2 + (ri >> 4);
  int bn = (rect >> 2) * 16 + (ri & 15);
  int srow = tid >> 3, schunk = tid & 7;
  int gcol = (schunk ^ (srow & 7)) * 8;   // pre-swizzled global chunk
  const bf16* Ag = A + (size_t)(bm * 256 + srow) * K + gcol;
  const bf16* Bg = B + (size_t)(bn * 256 + srow) * K + gcol;
  int soff = srow * 64 + schunk * 8;      // lane-linear LDS dest
  int fr = lane & 15, fq = lane >> 4;
  int c0 = ((fq) ^ (fr & 7)) * 8;         // slice0 swizzled chunk
  int c1 = ((4 + fq) ^ (fr & 7)) * 8;     // slice1
  const int arow = (wm * 128 + fr) * 64;
  const int brow = (wn * 64 + fr) * 64;

  GEMM_PIPE_BODY(K)

  int row0 = bm * 256 + wm * 128 + fq * 4;
  int col0 = bn * 256 + wn * 64 + fr;
#pragma unroll
  for (int i = 0; i < 8; i++)
#pragma unroll
    for (int j = 0; j < 4; j++)
#pragma unroll
      for (int r = 0; r < 4; r++)
        C[(size_t)(row0 + i * 16 + r) * N + col0 + j * 16] = acc[i][j][r];
}

// ---------------- split-K=2 variant for the output projection ----------------
// 224 blocks (87% util), K=2048 per half, lda=4096; partials to C + ks*M*N.
__global__ __launch_bounds__(512, 2) void gemm_nt_8p_ks(const bf16* __restrict__ A,
                                                        const bf16* __restrict__ B,
                                                        float* __restrict__ C,
                                                        int M, int N, int K, int lda) {
  __shared__ bf16 As0[256 * 64];
  __shared__ bf16 Bs0[256 * 64];
  __shared__ bf16 As1[256 * 64];
  __shared__ bf16 Bs1[256 * 64];
  int tid = threadIdx.x;
  int lane = tid & 63;
  int w = tid >> 6;
  int wm = w >> 2, wn = w & 3;
  int lid = blockIdx.x;
  int ks = lid >= 112;
  int l2 = lid - ks * 112;
  int oid = (l2 & 7) * 14 + (l2 >> 3);
  int bm = oid / 14;
  int bn = oid - bm * 14;
  int kbase = ks * K;
  float* Cp = C + (size_t)ks * M * N;
  int srow = tid >> 3, schunk = tid & 7;
  int gcol = (schunk ^ (srow & 7)) * 8;
  const bf16* Ag = A + (size_t)(bm * 256 + srow) * lda + kbase + gcol;
  const bf16* Bg = B + (size_t)(bn * 256 + srow) * lda + kbase + gcol;
  int soff = srow * 64 + schunk * 8;
  int fr = lane & 15, fq = lane >> 4;
  int c0 = ((fq) ^ (fr & 7)) * 8;
  int c1 = ((4 + fq) ^ (fr & 7)) * 8;
  const int arow = (wm * 128 + fr) * 64;
  const int brow = (wn * 64 + fr) * 64;

  GEMM_PIPE_BODY(lda)

  int row0 = bm * 256 + wm * 128 + fq * 4;
  int col0 = bn * 256 + wn * 64 + fr;
#pragma unroll
  for (int i = 0; i < 8; i++)
#pragma unroll
    for (int j = 0; j < 4; j++)
#pragma unroll
      for (int r = 0; r < 4; r++)
        Cp[(size_t)(row0 + i * 16 + r) * N + col0 + j * 16] = acc[i][j][r];
}

// ---------------- RMSNorm + RoPE + q-scale; one wave per (s, head) ----------------
__global__ __launch_bounds__(256) void qk_norm_rope(const float* __restrict__ qkv,
                                                    const float* __restrict__ cosb,
                                                    const float* __restrict__ sinb,
                                                    const float* __restrict__ qw,
                                                    const float* __restrict__ kw,
                                                    bf16* __restrict__ qout,
                                                    bf16* __restrict__ kout) {
  int s = blockIdx.x;
  int lane = threadIdx.x & 63;
  int w = threadIdx.x >> 6;
  int d0 = lane * 4;
  int dr = d0 & 127;
  f32x4 cv = *(const f32x4*)(cosb + s * 128 + dr);
  f32x4 sv = *(const f32x4*)(sinb + s * 128 + dr);
  bool hi = lane >= 32;
#pragma unroll
  for (int r = 0; r < 6; r++) {
    int head = r * 4 + w;  // 0..23 : 16 q heads then 8 k heads
    const float* x = qkv + (size_t)s * QKV_O + head * HDIM + d0;
    f32x4 v = *(const f32x4*)x;
    float ss = v[0] * v[0] + v[1] * v[1] + v[2] * v[2] + v[3] * v[3];
#pragma unroll
    for (int off = 32; off > 0; off >>= 1) ss += __shfl_xor(ss, off);
    float scale = rsqrtf(ss * (1.0f / HDIM) + 1e-6f);
    bool isq = head < NHEADS;
    const float* wn = isq ? qw : kw;
    f32x4 wv = *(const f32x4*)(wn + d0);
    float y[4], o[4];
#pragma unroll
    for (int i = 0; i < 4; i++) y[i] = v[i] * scale * (1.0f + wv[i]);
#pragma unroll
    for (int i = 0; i < 4; i++) {
      float py = __shfl_xor(y[i], 32);
      o[i] = hi ? (py * sv[i] + y[i] * cv[i]) : (y[i] * cv[i] - py * sv[i]);
    }
    float mult = isq ? 0.0625f : 1.0f;  // SCALING = 256^-0.5 folded into q
    bf16x4 ov = { (bf16)(o[0] * mult), (bf16)(o[1] * mult), (bf16)(o[2] * mult), (bf16)(o[3] * mult) };
    if (isq) *(bf16x4*)(qout + ((size_t)head * S_LEN + s) * HDIM + d0) = ov;
    else     *(bf16x4*)(kout + ((size_t)(head - NHEADS) * S_LEN + s) * HDIM + d0) = ov;
  }
}

// ---------------- V transpose: qkv fp32 [s][6144+h*256+d] -> vt bf16 [h][d][s] ----------------
__global__ __launch_bounds__(256) void v_transpose(const float* __restrict__ qkv, bf16* __restrict__ vt) {
  __shared__ float tile[64][65];
  int dt = blockIdx.x, st = blockIdx.y, h = blockIdx.z;
  int t = threadIdx.x;
  int d0 = dt * 64, s0 = st * 64;
#pragma unroll
  for (int i = 0; i < 16; i++) {
    int idx = i * 256 + t;
    int r = idx >> 6, c = idx & 63;
    tile[r][c] = qkv[(size_t)(s0 + r) * QKV_O + 6144 + h * HDIM + d0 + c];
  }
  __syncthreads();
#pragma unroll
  for (int i = 0; i < 16; i++) {
    int idx = i * 256 + t;
    int dr = idx >> 6, sc = idx & 63;
    vt[((size_t)h * HDIM + d0 + dr) * S_LEN + s0 + sc] = (bf16)tile[sc][dr];
  }
}

// ---------------- Flash attention: 64 q-rows/block, Bk=32 ----------------
#define PSTRIDE 40
__global__ __launch_bounds__(256) void attn_kernel(const bf16* __restrict__ q,
                                                   const bf16* __restrict__ kx,
                                                   const bf16* __restrict__ vt,
                                                   bf16* __restrict__ aout) {
  __shared__ bf16 kt[32 * 256];
  __shared__ bf16 vtile[256 * 32];
  __shared__ bf16 pbuf[4][16 * PSTRIDE];
  int h = blockIdx.x;
  int y = blockIdx.y;
  int qt = (y < 16) ? y : 47 - y;
  int kvh = h >> 1;
  int tid = threadIdx.x;
  int lane = tid & 63, w = tid >> 6;
  int fr = lane & 15, fq = lane >> 4;
  int qs = qt * 64;
  bf16x8 qf[8];
  const bf16* qb = q + ((size_t)h * S_LEN + qs + w * 16 + fr) * HDIM + fq * 8;
#pragma unroll
  for (int i = 0; i < 8; i++) qf[i] = *(const bf16x8*)(qb + i * 32);
  f32x4 acc[16];
#pragma unroll
  for (int i = 0; i < 16; i++) { f32x4 z = {0.f, 0.f, 0.f, 0.f}; acc[i] = z; }
  float lsum[4] = {0.f, 0.f, 0.f, 0.f};
  int krow = w * 2 + (lane >> 5);
  int kcolr = (lane & 31) * 8;
  const bf16* kg = kx + (size_t)kvh * S_LEN * HDIM;
  int vd = w * 16 + (lane >> 2);
  int vsw = (vd >> 1) & 3;
  int vcl = (lane & 3) * 8;
  int vcg = (((lane & 3) ^ vsw) * 8);
  const bf16* vg = vt + (size_t)kvh * HDIM * S_LEN;
  int rot0 = (fq * 8 - fr * 8) & 255;
  int rot1 = (fq * 8 - fr * 8 - 128) & 255;
  const bf16* kt0 = &kt[fr * 256];
  const bf16* kt1 = &kt[(16 + fr) * 256];
  int fsw = (fr >> 1) & 3;
  int kmax = qs + 64;
  for (int k0 = 0; k0 < kmax; k0 += 32) {
    __syncthreads();
#pragma unroll
    for (int p = 0; p < 4; p++) {
      int r = p * 8 + krow;
      int gc = (kcolr + r * 8) & 255;
      async16(kg + (size_t)(k0 + r) * HDIM + gc, &kt[r * 256 + kcolr]);
      int d = p * 64 + vd;
      async16(vg + (size_t)d * S_LEN + k0 + vcg, &vtile[d * 32 + vcl]);
    }
    __syncthreads();
    f32x4 s0 = {0.f, 0.f, 0.f, 0.f}, s1 = {0.f, 0.f, 0.f, 0.f};
#pragma unroll
    for (int kk = 0; kk < 8; kk++) {
      bf16x8 b0 = *(const bf16x8*)(kt0 + ((kk * 32 + rot0) & 255));
      bf16x8 b1 = *(const bf16x8*)(kt1 + ((kk * 32 + rot1) & 255));
      s0 = mfma16(qf[kk], b0, s0);
      s1 = mfma16(qf[kk], b1, s1);
    }
#pragma unroll
    for (int reg = 0; reg < 4; reg++) {
      int rowg = qs + w * 16 + fq * 4 + reg;
      float u0 = __builtin_amdgcn_exp2f(0.057707802f * s0[reg]);
      float u1 = __builtin_amdgcn_exp2f(0.057707802f * s1[reg]);
      float p0 = __builtin_amdgcn_exp2f(28.853901f - 144.26950f * __builtin_amdgcn_rcpf(u0 + 1.0f));
      float p1 = __builtin_amdgcn_exp2f(28.853901f - 144.26950f * __builtin_amdgcn_rcpf(u1 + 1.0f));
      p0 = (k0 + fr <= rowg) ? p0 : 0.0f;
      p1 = (k0 + 16 + fr <= rowg) ? p1 : 0.0f;
      lsum[reg] += p0 + p1;
      pbuf[w][(fq * 4 + reg) * PSTRIDE + fr] = (bf16)p0;
      pbuf[w][(fq * 4 + reg) * PSTRIDE + 16 + fr] = (bf16)p1;
    }
    bf16x8 pf = *(const bf16x8*)&pbuf[w][fr * PSTRIDE + fq * 8];
#pragma unroll
    for (int ct = 0; ct < 16; ct++) {
      bf16x8 vf = *(const bf16x8*)&vtile[(ct * 16 + fr) * 32 + (fq ^ fsw) * 8];
      acc[ct] = mfma16(pf, vf, acc[ct]);
    }
  }
  float rl[4];
#pragma unroll
  for (int reg = 0; reg < 4; reg++) {
    float l = lsum[reg];
    l += __shfl_xor(l, 1);
    l += __shfl_xor(l, 2);
    l += __shfl_xor(l, 4);
    l += __shfl_xor(l, 8);
    rl[reg] = 1.0f / l;
  }
#pragma unroll
  for (int ct = 0; ct < 16; ct++)
#pragma unroll
    for (int reg = 0; reg < 4; reg++)
      aout[(size_t)(qs + w * 16 + fq * 4 + reg) * O_IN + h * HDIM + ct * 16 + fr] =
          (bf16)(acc[ct][reg] * rl[reg]);
}

extern "C" void kernel_launch(void* const* d_in, const int* in_sizes, int n_in,
                              void* d_out, int out_size, void* d_ws, size_t ws_size,
                              hipStream_t stream) {
  const float* hidden = (const float*)d_in[0];
  const float* cosb   = (const float*)d_in[1];
  const float* sinb   = (const float*)d_in[2];
  const float* wqkv   = (const float*)d_in[7];
  const float* wo     = (const float*)d_in[8];
  const float* qnw    = (const float*)d_in[9];
  const float* knw    = (const float*)d_in[10];
  float* out = (float*)d_out;
  char* ws = (char*)d_ws;
  bf16*  h_bf    = (bf16*)(ws + 0);          // 2048*3584*2   = 14,680,064
  bf16*  wqkv_bf = (bf16*)(ws + 14680064);   // 8192*3584*2   = 58,720,256
  bf16*  wo_bf   = (bf16*)(ws + 73400320);   // 3584*4096*2   = 29,360,128
  float* qkv     = (float*)(ws + 102760448); // 2048*8192*4   = 67,108,864
  bf16*  qb      = (bf16*)(ws + 169869312);  // 16*2048*256*2 = 16,777,216
  bf16*  kb      = (bf16*)(ws + 186646528);  // 8*2048*256*2  =  8,388,608
  bf16*  vtb     = (bf16*)(ws + 195035136);  // 8*256*2048*2  =  8,388,608
  bf16*  attnb   = (bf16*)(ws + 203423744);  // 2048*4096*2   = 16,777,216
  // split-K partials reuse the qkv region (dead after qk_norm_rope + v_transpose)
  float* part0   = (float*)(ws + 102760448);
  float* part1   = part0 + (size_t)2048 * 3584;

  cast_kernel<<<7168, 256, 0, stream>>>(hidden, h_bf, 1835008);
  cast_kernel<<<28672, 256, 0, stream>>>(wqkv, wqkv_bf, 7340032);
  cast_kernel<<<14336, 256, 0, stream>>>(wo, wo_bf, 3670016);
  gemm_nt_8p<<<256, 512, 0, stream>>>(h_bf, wqkv_bf, qkv, 2048, 8192, 3584);
  qk_norm_rope<<<2048, 256, 0, stream>>>(qkv, cosb, sinb, qnw, knw, qb, kb);
  v_transpose<<<dim3(4, 32, 8), 256, 0, stream>>>(qkv, vtb);
  attn_kernel<<<dim3(16, 32), 256, 0, stream>>>(qb, kb, vtb, attnb);
  gemm_nt_8p_ks<<<224, 512, 0, stream>>>(attnb, wo_bf, part0, 2048, 3584, 2048, 4096);
  add2_kernel<<<7168, 256, 0, stream>>>(part0, part1, out, 1835008);
}